// Round 15
// baseline (278.689 us; speedup 1.0000x reference)
//
#include <hip/hip_runtime.h>

// Linear RNN scan: h_t = h_{t-1}@A + x_t@B ; y_t = h_t@C
// B=8, S=4096, IN=STATE=OUT=256.
// MFMA 16x16x32 f16, 2-term split (hi + 2048*lo), f32 accumulate.
// Swapped operands; slice-linear LDS (slot ((ak<<4)|row)^s) -> conflict-free.
// Round-13 compute bodies. NEW: launch-count reduction via manual grid-sync
// mega-kernels (counters zeroed by hipMemsetAsync; 64/32-block grids are
// always co-resident on 256 CUs):
//   power_chain: 9 f32 squarings (A^8/A^64/A^512) + frag pack   [1 launch]
//   spine_scan : L1c -> L2c -> top -> L2a -> L1a (37 steps)     [1 launch]
// Total 7 kernels + 1 memset (was 18 kernels).

#define SEQ    4096
#define NBATCH 8
#define ND     256
#define CHUNK  8
#define NCHUNK 512
#define LOSC   2048.0f
#define LOINV  (1.0f/2048.0f)

typedef _Float16 fp16_t;
typedef __attribute__((ext_vector_type(8))) _Float16 f16x8;
typedef __attribute__((ext_vector_type(4))) _Float16 f16x4;
typedef __attribute__((ext_vector_type(4))) float f32x4;

// ---------- manual grid sync (device-scope; grid must be co-resident) ----------
__device__ __forceinline__ void gsync(unsigned* c, unsigned target) {
  __syncthreads();
  if (threadIdx.x == 0) {
    __threadfence();                       // release: flush writes device-wide
    atomicAdd(c, 1u);
    while (__hip_atomic_load(c, __ATOMIC_ACQUIRE, __HIP_MEMORY_SCOPE_AGENT) < target)
      __builtin_amdgcn_s_sleep(8);
    __threadfence();                       // acquire: invalidate stale cache
  }
  __syncthreads();
}

// ---------- pack three 256x256 f32 matrices into frag arrays (hi/lo f16) ----------
// frag linear index: ((tile*8 + slice)*64 + lane)*8 + j
// value = M[k][n], k = slice*32 + (lane>>4)*8 + j, n = tile*16 + (lane&15)
__device__ __forceinline__ void prep_unit(const float* M, fp16_t* hi, fp16_t* lo,
                                          int blk, int lane) {
  const int tile = blk >> 3, slice = blk & 7;
  const int n  = tile * 16 + (lane & 15);
  const int k0 = slice * 32 + (lane >> 4) * 8;
  f16x8 vh, vl;
  #pragma unroll
  for (int j = 0; j < 8; ++j) {
    const float v = M[(size_t)(k0 + j) * ND + n];
    const fp16_t h = (fp16_t)v;
    vh[j] = h;
    vl[j] = (fp16_t)((v - (float)h) * LOSC);
  }
  const size_t fo = ((size_t)blk * 64 + lane) * 8;
  *(f16x8*)&hi[fo] = vh;
  *(f16x8*)&lo[fo] = vl;
}

__global__ __launch_bounds__(64) void prep_frags3(
    const float* __restrict__ A, const float* __restrict__ B,
    const float* __restrict__ C,
    fp16_t* __restrict__ fAh, fp16_t* __restrict__ fAl,
    fp16_t* __restrict__ fBh, fp16_t* __restrict__ fBl,
    fp16_t* __restrict__ fCh, fp16_t* __restrict__ fCl) {
  const int which = blockIdx.x >> 7;
  const int blk   = blockIdx.x & 127;
  const float* M = (which == 0) ? A : (which == 1) ? B : C;
  fp16_t* hi = (which == 0) ? fAh : (which == 1) ? fBh : fCh;
  fp16_t* lo = (which == 0) ? fAl : (which == 1) ? fBl : fCl;
  prep_unit(M, hi, lo, blk, threadIdx.x);
}

// ---------- f32 GEMM body (256 threads, 64 blocks, 4 rows/block) ----------
__device__ __forceinline__ void gemm_body(const float* X, const float* Y,
                                          float* Out, float (*Xs)[4]) {
  const int m0 = blockIdx.x * 4;
  const int n  = threadIdx.x;
  #pragma unroll
  for (int r = 0; r < 4; ++r) Xs[n][r] = X[(m0 + r) * ND + n];
  __syncthreads();
  float a0 = 0.f, a1 = 0.f, a2 = 0.f, a3 = 0.f;
  #pragma unroll 8
  for (int k = 0; k < ND; ++k) {
    const float yv = Y[k * ND + n];
    const float4 xv = *(const float4*)&Xs[k][0];
    a0 = fmaf(xv.x, yv, a0);
    a1 = fmaf(xv.y, yv, a1);
    a2 = fmaf(xv.z, yv, a2);
    a3 = fmaf(xv.w, yv, a3);
  }
  Out[(m0 + 0) * ND + n] = a0;
  Out[(m0 + 1) * ND + n] = a1;
  Out[(m0 + 2) * ND + n] = a2;
  Out[(m0 + 3) * ND + n] = a3;
}

// ---------- fused power chain: A^8, A^64, A^512 + frag pack  [64 blocks] ----------
__global__ __launch_bounds__(256) void power_chain(
    const float* __restrict__ A,
    float* q1, float* q2, float* q3, float* q4, float* q5, float* q6,
    float* A8f, float* A64f, float* A512f,
    fp16_t* fA8h, fp16_t* fA8l, fp16_t* fA64h, fp16_t* fA64l,
    fp16_t* fA512h, fp16_t* fA512l,
    unsigned* sync) {
  __shared__ float Xs[ND][4];
  gemm_body(A,    A,    q1,    Xs);  gsync(sync + 0, 64);   // A^2
  gemm_body(q1,   q1,   q2,    Xs);  gsync(sync + 1, 64);   // A^4
  gemm_body(q2,   q2,   A8f,   Xs);  gsync(sync + 2, 64);   // A^8
  gemm_body(A8f,  A8f,  q3,    Xs);  gsync(sync + 3, 64);   // A^16
  gemm_body(q3,   q3,   q4,    Xs);  gsync(sync + 4, 64);   // A^32
  gemm_body(q4,   q4,   A64f,  Xs);  gsync(sync + 5, 64);   // A^64
  gemm_body(A64f, A64f, q5,    Xs);  gsync(sync + 6, 64);   // A^128
  gemm_body(q5,   q5,   q6,    Xs);  gsync(sync + 7, 64);   // A^256
  gemm_body(q6,   q6,   A512f, Xs);  gsync(sync + 8, 64);   // A^512
  // frag pack for A^8 / A^64 / A^512: 384 wave-units over 256 waves
  const int gw   = blockIdx.x * 4 + (threadIdx.x >> 6);
  const int lane = threadIdx.x & 63;
  for (int u = gw; u < 384; u += 256) {
    const int which = u >> 7;
    const int blk   = u & 127;
    const float* M = (which == 0) ? A8f : (which == 1) ? A64f : A512f;
    fp16_t* hi = (which == 0) ? fA8h : (which == 1) ? fA64h : fA512h;
    fp16_t* lo = (which == 0) ? fA8l : (which == 1) ? fA64l : fA512l;
    prep_unit(M, hi, lo, blk, lane);
  }
}

// ---------- MFMA GEMM: Out[m][:] = X[m][:] @ M,  m = s*8+b, M-block = 64 ----------
// mode 0 (xb): X rows remapped from x[b][s][:];  mode 1 (y): Out remapped to y[b][s][:]
__global__ __launch_bounds__(1024, 2) void mfma_gemm(const float* __restrict__ X,
                                                     const fp16_t* __restrict__ Mhi,
                                                     const fp16_t* __restrict__ Mlo,
                                                     float* __restrict__ Out,
                                                     int mode) {
  const int m0   = blockIdx.x * 64;
  const int tid  = threadIdx.x;
  const int lane = tid & 63;
  const int w    = tid >> 6;          // 16 waves, M-col tile w
  const int br   = lane & 15;
  const int akg  = lane >> 4;

  __shared__ fp16_t Xh[32 * 512];     // 32 regions x 1024B (slice-linear)
  __shared__ fp16_t Xl[32 * 512];
  char* Xhb = (char*)Xh;
  char* Xlb = (char*)Xl;

  #pragma unroll
  for (int pass = 0; pass < 2; ++pass) {
    const int tau = pass * 1024 + tid;
    const int row = tau >> 5;         // 0..63
    const int sub = tau & 31;
    const int s   = sub >> 2;
    const int ak  = sub & 3;
    const int m = m0 + row;
    const size_t in_row = (mode == 0)
        ? ((size_t)(m & 7) * SEQ + (m >> 3))
        : (size_t)m;
    const float* xp = &X[in_row * ND + s * 32 + ak * 8];
    const float4 x0 = *(const float4*)(xp);
    const float4 x1 = *(const float4*)(xp + 4);
    const float a[8] = {x0.x, x0.y, x0.z, x0.w, x1.x, x1.y, x1.z, x1.w};
    f16x8 vh, vl;
    #pragma unroll
    for (int j = 0; j < 8; ++j) {
      const fp16_t h = (fp16_t)a[j];
      vh[j] = h;
      vl[j] = (fp16_t)((a[j] - (float)h) * LOSC);
    }
    const int off = (((row >> 4) * 8 + s) << 10) +
                    (((ak << 4) | (row & 15)) ^ s) * 16;
    *(f16x8*)(Xhb + off) = vh;
    *(f16x8*)(Xlb + off) = vl;
  }

  f16x8 MH[8], ML[8];
  #pragma unroll
  for (int s = 0; s < 8; ++s) {
    const size_t fo = (((size_t)w * 8 + s) * 64 + lane) * 8;
    MH[s] = *(const f16x8*)&Mhi[fo];
    ML[s] = *(const f16x8*)&Mlo[fo];
  }
  __syncthreads();

  f32x4 accm[4], accl[4];
  #pragma unroll
  for (int mt = 0; mt < 4; ++mt) {
    accm[mt] = (f32x4)0.0f;
    accl[mt] = (f32x4)0.0f;
  }

  #pragma unroll
  for (int s = 0; s < 8; ++s) {
    #pragma unroll
    for (int mt = 0; mt < 4; ++mt) {
      const int byte = ((mt * 8 + s) << 10) + ((((akg << 4) | br) ^ s) << 4);
      const f16x8 bh = *(const f16x8*)(Xhb + byte);
      const f16x8 bl = *(const f16x8*)(Xlb + byte);
      accm[mt] = __builtin_amdgcn_mfma_f32_16x16x32_f16(MH[s], bh, accm[mt], 0, 0, 0);
      accl[mt] = __builtin_amdgcn_mfma_f32_16x16x32_f16(ML[s], bh, accl[mt], 0, 0, 0);
      accl[mt] = __builtin_amdgcn_mfma_f32_16x16x32_f16(MH[s], bl, accl[mt], 0, 0, 0);
    }
  }

  #pragma unroll
  for (int mt = 0; mt < 4; ++mt) {
    const int m = m0 + mt * 16 + br;            // output row (X-row)
    const size_t out_row = (mode == 1)
        ? ((size_t)(m & 7) * SEQ + (m >> 3))
        : (size_t)m;
    float4 o;
    o.x = accm[mt][0] + accl[mt][0] * LOINV;
    o.y = accm[mt][1] + accl[mt][1] * LOINV;
    o.z = accm[mt][2] + accl[mt][2] * LOINV;
    o.w = accm[mt][3] + accl[mt][3] * LOINV;
    *(float4*)&Out[out_row * ND + w * 16 + akg * 4] = o;
  }
}

// ---------- unified MFMA recurrence body (swapped operands) ----------
// Block runs TWO independent 8-row sequences (seq = blockIdx.x*2 + rowgrp).
// For nupd steps: h = h @ Mult + In[(seq*gstride + j)*NB + b].
__device__ __forceinline__ void rscan_body(
    const fp16_t* Mh, const fp16_t* Ml,
    const float* Init, const float* In, float* OutEach, float* OutFinal,
    int nupd, int gstride, int nseq, int init_bcast, int entry_mode,
    fp16_t (*hH)[8 * 512], fp16_t (*hL)[8 * 512]) {
  const int seq0 = blockIdx.x * 2;
  const int tid  = threadIdx.x;
  const int lane = tid & 63;
  const int w    = tid >> 6;          // 16 waves, state-col tile w
  const int br   = lane & 15;         // batch row 0..15
  const int akg  = lane >> 4;

  // init h (buf 0), slice-linear
  {
    const int task = tid >> 1;        // 0..511
    const int half = tid & 1;
    const int row  = task & 15;
    const int s    = (task >> 4) & 7;
    const int ak   = task >> 7;       // 0..3
    const int sq = seq0 + (row >> 3);
    const int b  = row & 7;
    const int c0 = s * 32 + ak * 8 + half * 4;
    f32x4 v = (f32x4)0.0f;
    if (Init != nullptr && sq < nseq) {
      const size_t off = init_bcast ? (size_t)c0
                                    : ((size_t)sq * NBATCH + b) * ND + c0;
      v = *(const f32x4*)&Init[off];
      if (entry_mode && OutEach != nullptr)
        *(f32x4*)&OutEach[((size_t)sq * gstride * NBATCH + b) * ND + c0] = v;
    }
    f16x4 vh, vl;
    #pragma unroll
    for (int j = 0; j < 4; ++j) {
      const fp16_t h = (fp16_t)v[j];
      vh[j] = h;
      vl[j] = (fp16_t)((v[j] - (float)h) * LOSC);
    }
    const int off = (s << 10) + ((((ak << 4) | row) ^ s) << 4) + half * 8;
    *(f16x4*)((char*)hH[0] + off) = vh;
    *(f16x4*)((char*)hL[0] + off) = vl;
  }

  // A^T frags (A-operand) for this wave's state-col tile (L2-resident reloads)
  f16x8 AH[8], AL[8];
  #pragma unroll
  for (int s = 0; s < 8; ++s) {
    const size_t fo = (((size_t)w * 8 + s) * 64 + lane) * 8;
    AH[s] = *(const f16x8*)&Mh[fo];
    AL[s] = *(const f16x8*)&Ml[fo];
  }
  __syncthreads();

  const int sq   = seq0 + (br >> 3);
  const int b    = br & 7;
  const bool live = (sq < nseq);
  const int sqc  = live ? sq : (nseq - 1);     // clamp for safe loads
  const int col0 = w * 16 + akg * 4;

  int rdoff[8];
  #pragma unroll
  for (int s = 0; s < 8; ++s)
    rdoff[s] = (s << 10) + ((((akg << 4) | br) ^ s) << 4);
  const int sw   = col0 >> 5;
  const int akr  = (col0 >> 3) & 3;
  const int wroff = (sw << 10) + ((((akr << 4) | br) ^ sw) << 4) + (col0 & 7) * 2;

  f32x4 uv = *(const f32x4*)&In[((size_t)(sqc * gstride) * NBATCH + b) * ND + col0];
  f32x4 uvn;
  f32x4 res;
  int p = 0;
  for (int j = 0; j < nupd; ++j) {
    if (j + 1 < nupd)
      uvn = *(const f32x4*)&In[((size_t)(sqc * gstride + j + 1) * NBATCH + b) * ND + col0];
    const char* rH = (const char*)hH[p];
    const char* rL = (const char*)hL[p];
    f32x4 accm = uv, acclA = (f32x4)0.0f, acclB = (f32x4)0.0f;
    #pragma unroll
    for (int s = 0; s < 8; ++s) {
      const f16x8 bh = *(const f16x8*)(rH + rdoff[s]);
      const f16x8 bl = *(const f16x8*)(rL + rdoff[s]);
      accm  = __builtin_amdgcn_mfma_f32_16x16x32_f16(AH[s], bh, accm,  0, 0, 0);
      acclA = __builtin_amdgcn_mfma_f32_16x16x32_f16(AL[s], bh, acclA, 0, 0, 0);
      acclB = __builtin_amdgcn_mfma_f32_16x16x32_f16(AH[s], bl, acclB, 0, 0, 0);
    }
    #pragma unroll
    for (int r = 0; r < 4; ++r) res[r] = accm[r] + (acclA[r] + acclB[r]) * LOINV;
    // write new h into the OTHER buffer (no barrier needed before writes)
    {
      f16x4 vh, vl;
      #pragma unroll
      for (int r = 0; r < 4; ++r) {
        const fp16_t hh = (fp16_t)res[r];
        vh[r] = hh;
        vl[r] = (fp16_t)((res[r] - (float)hh) * LOSC);
      }
      *(f16x4*)((char*)hH[p ^ 1] + wroff) = vh;
      *(f16x4*)((char*)hL[p ^ 1] + wroff) = vl;
    }
    if (OutEach != nullptr && live) {
      const size_t pos = entry_mode ? (size_t)(sq * gstride + j + 1)
                                    : (size_t)(sq * gstride + j);
      *(f32x4*)&OutEach[(pos * NBATCH + b) * ND + col0] = res;
    }
    uv = uvn;
    p ^= 1;
    __syncthreads();                  // new h visible; old buf free for reuse
  }

  if (OutFinal != nullptr && live)
    *(f32x4*)&OutFinal[((size_t)sq * NBATCH + b) * ND + col0] = res;
}

// ---------- standalone recurrence kernel (chunk passes, 256 blocks) ----------
__global__ __launch_bounds__(1024, 2) void mfma_rscan(
    const fp16_t* __restrict__ Mh, const fp16_t* __restrict__ Ml,
    const float* __restrict__ Init,
    const float* In,
    float* OutEach,
    float* __restrict__ OutFinal,
    int nupd, int gstride, int nseq, int init_bcast, int entry_mode) {
  __shared__ fp16_t hH[2][8 * 512];
  __shared__ fp16_t hL[2][8 * 512];
  rscan_body(Mh, Ml, Init, In, OutEach, OutFinal,
             nupd, gstride, nseq, init_bcast, entry_mode, hH, hL);
}

// ---------- fused spine: L1c -> L2c -> top -> L2a -> L1a  [32 blocks] ----------
__global__ __launch_bounds__(1024, 2) void spine_scan(
    const fp16_t* __restrict__ fA8h, const fp16_t* __restrict__ fA8l,
    const fp16_t* __restrict__ fA64h, const fp16_t* __restrict__ fA64l,
    const fp16_t* __restrict__ fA512h, const fp16_t* __restrict__ fA512l,
    const float* __restrict__ h0, const float* __restrict__ E,
    float* S1, float* S2, float* G3, float* Hc2, float* Hc,
    unsigned* sync) {
  __shared__ fp16_t hH[2][8 * 512];
  __shared__ fp16_t hL[2][8 * 512];
  // L1 collect: 64 seqs of 8 chunk-ends, mult A^8
  rscan_body(fA8h, fA8l, nullptr, E, nullptr, S1, 8, 8, 64, 0, 0, hH, hL);
  gsync(sync + 16, 32);
  // L2 collect: 8 seqs of 8 group-sums, mult A^64
  rscan_body(fA64h, fA64l, nullptr, S1, nullptr, S2, 8, 8, 8, 0, 0, hH, hL);
  gsync(sync + 17, 32);
  // top: 1 seq of 7 steps from h0, mult A^512 -> G3[0..7]
  rscan_body(fA512h, fA512l, h0, S2, G3, nullptr, 7, 8, 1, 1, 1, hH, hL);
  gsync(sync + 18, 32);
  // L2 apply: entries for 64 L1 groups, mult A^64 -> Hc2
  rscan_body(fA64h, fA64l, G3, S1, Hc2, nullptr, 7, 8, 8, 0, 1, hH, hL);
  gsync(sync + 19, 32);
  // L1 apply: entries for 512 chunks, mult A^8 -> Hc
  rscan_body(fA8h, fA8l, Hc2, E, Hc, nullptr, 7, 8, 64, 0, 1, hH, hL);
}

extern "C" void kernel_launch(void* const* d_in, const int* in_sizes, int n_in,
                              void* d_out, int out_size, void* d_ws, size_t ws_size,
                              hipStream_t stream) {
  const float* x  = (const float*)d_in[0];
  const float* A  = (const float*)d_in[1];
  const float* Bm = (const float*)d_in[2];
  const float* Cm = (const float*)d_in[3];
  const float* h0 = (const float*)d_in[4];
  float* y = (float*)d_out;

  float* U     = (float*)d_ws;                        // 8,388,608
  float* q1    = U + (size_t)SEQ * NBATCH * ND;
  float* q2    = q1 + ND * ND;
  float* q3    = q2 + ND * ND;
  float* q4    = q3 + ND * ND;
  float* q5    = q4 + ND * ND;
  float* q6    = q5 + ND * ND;
  float* A8f   = q6 + ND * ND;
  float* A64f  = A8f + ND * ND;
  float* A512f = A64f + ND * ND;
  float* E     = A512f + ND * ND;                     // [512][8][256]
  float* S1    = E + (size_t)NCHUNK * NBATCH * ND;    // [64][8][256]
  float* S2    = S1 + (size_t)64 * NBATCH * ND;       // [8][8][256]
  float* G3    = S2 + (size_t)8 * NBATCH * ND;        // [8][8][256]
  float* Hc2   = G3 + (size_t)8 * NBATCH * ND;        // [64][8][256]
  float* Hc    = Hc2 + (size_t)64 * NBATCH * ND;      // [512][8][256]
  fp16_t* fA_hi   = (fp16_t*)(Hc + (size_t)NCHUNK * NBATCH * ND);
  fp16_t* fA_lo   = fA_hi + ND * ND;
  fp16_t* fB_hi   = fA_lo + ND * ND;
  fp16_t* fB_lo   = fB_hi + ND * ND;
  fp16_t* fC_hi   = fB_lo + ND * ND;
  fp16_t* fC_lo   = fC_hi + ND * ND;
  fp16_t* fA8_hi  = fC_lo + ND * ND;
  fp16_t* fA8_lo  = fA8_hi + ND * ND;
  fp16_t* fA64_hi = fA8_lo + ND * ND;
  fp16_t* fA64_lo = fA64_hi + ND * ND;
  fp16_t* fA512_hi = fA64_lo + ND * ND;
  fp16_t* fA512_lo = fA512_hi + ND * ND;
  unsigned* sync = (unsigned*)(fA512_lo + ND * ND);   // 32 counters

  // zero sync counters (graph-capture-safe memset node)
  hipMemsetAsync(sync, 0, 32 * sizeof(unsigned), stream);

  // pack A,B,C into fragment arrays
  prep_frags3<<<384, 64, 0, stream>>>(A, Bm, Cm, fA_hi, fA_lo, fB_hi, fB_lo,
                                      fC_hi, fC_lo);

  // fused power chain: A^8, A^64, A^512 (f32) + frag pack   [1 launch]
  power_chain<<<64, 256, 0, stream>>>(A, q1, q2, q3, q4, q5, q6,
                                      A8f, A64f, A512f,
                                      fA8_hi, fA8_lo, fA64_hi, fA64_lo,
                                      fA512_hi, fA512_lo, sync);

  // U = x @ B
  mfma_gemm<<<512, 1024, 0, stream>>>(x, fB_hi, fB_lo, U, 0);

  // chunk local ends: E[c] = scan(0; u over chunk c)     [256 blocks]
  mfma_rscan<<<NCHUNK / 2, 1024, 0, stream>>>(fA_hi, fA_lo, nullptr, U,
                                              nullptr, E, 8, 8, NCHUNK, 0, 0);

  // fused spine (radix 8/8/8, manual grid sync)           [1 launch]
  spine_scan<<<32, 1024, 0, stream>>>(fA8_hi, fA8_lo, fA64_hi, fA64_lo,
                                      fA512_hi, fA512_lo, h0, E,
                                      S1, S2, G3, Hc2, Hc, sync);

  // final chunk scan from true entries; h overwrites U   [256 blocks]
  mfma_rscan<<<NCHUNK / 2, 1024, 0, stream>>>(fA_hi, fA_lo, Hc, U,
                                              U, nullptr, 8, 8, NCHUNK, 0, 0);

  // y = h @ C
  mfma_gemm<<<512, 1024, 0, stream>>>(U, fC_hi, fC_lo, y, 1);
}